// Round 1
// baseline (121.883 us; speedup 1.0000x reference)
//
#include <hip/hip_runtime.h>

#define TIMESTEPS 32

// One thread handles 4 consecutive input elements (one float4) and writes
// 32 float4 outputs, one per timestep. For a fixed t, lanes of a wave write
// consecutive float4s -> fully coalesced 16B/lane global_store_dwordx4.
__global__ __launch_bounds__(256) void LatencyCoding_kernel(
    const float* __restrict__ x, float* __restrict__ out,
    int n4, int spatial /* C*H*W, multiple of 4 */) {

    int idx4 = blockIdx.x * blockDim.x + threadIdx.x;
    if (idx4 >= n4) return;

    float4 v = reinterpret_cast<const float4*>(x)[idx4];

    int elem = idx4 << 2;                 // flat input element index = b*spatial + s
    int b    = elem / spatial;            // batch index
    int s    = elem - b * spatial;        // spatial offset within the image

    float comp[4] = {v.x, v.y, v.z, v.w};
    int   lat[4];
    bool  on[4];
#pragma unroll
    for (int j = 0; j < 4; ++j) {
        float xn = fminf(fmaxf(comp[j], 0.0f), 1.0f);   // clip(x, 0, 1)
        int l = (int)((1.0f - xn) * 31.0f);             // trunc, same fp32 ops as ref
        l = min(max(l, 0), TIMESTEPS - 1);
        lat[j] = l;
        on[j]  = (xn > 0.0f);
    }

    // Output base: out[b][t][s], layout [B, T, spatial]
    float4* out4 = reinterpret_cast<float4*>(out + (size_t)b * TIMESTEPS * spatial + s);
    size_t stride4 = (size_t)(spatial >> 2);            // float4s per timestep plane

#pragma unroll
    for (int t = 0; t < TIMESTEPS; ++t) {
        float4 o;
        o.x = (on[0] && lat[0] == t) ? 1.0f : 0.0f;
        o.y = (on[1] && lat[1] == t) ? 1.0f : 0.0f;
        o.z = (on[2] && lat[2] == t) ? 1.0f : 0.0f;
        o.w = (on[3] && lat[3] == t) ? 1.0f : 0.0f;
        out4[(size_t)t * stride4] = o;
    }
}

extern "C" void kernel_launch(void* const* d_in, const int* in_sizes, int n_in,
                              void* d_out, int out_size, void* d_ws, size_t ws_size,
                              hipStream_t stream) {
    const float* x  = (const float*)d_in[0];
    float*       out = (float*)d_out;

    int n = in_sizes[0];           // 32*3*224*224 = 4,816,896
    int spatial = n / 32;          // B = 32 -> 150,528 (divisible by 4)
    int n4 = n / 4;                // 1,204,224 threads

    const int block = 256;
    int grid = (n4 + block - 1) / block;
    LatencyCoding_kernel<<<grid, block, 0, stream>>>(x, out, n4, spatial);
}